// Round 11
// baseline (63.944 us; speedup 1.0000x reference)
//
#include <hip/hip_runtime.h>
#include <cstdint>

constexpr int N_NODES = 2048;
constexpr int N_EDGES = 16384;
constexpr int NGRP    = 8;                  // float4 groups per block -> 32 edges
constexpr int TILE_E  = NGRP * 4;           // 32 edges per block
constexpr int WAVES   = 8;
constexpr int BLK     = WAVES * 64;         // 512 threads
constexpr int KSUB    = 8;                  // in-wave k-split (lane>>3)
constexpr int ROWS_W  = N_NODES / WAVES;    // 256 rows per wave
constexpr int ROWS_T  = ROWS_W / KSUB;      // 32 rows per thread
constexpr int NBLK    = N_EDGES / TILE_E;   // 512 blocks -> 2 blocks/CU

// LDS union: phase 1 uses xs (X staged, 32768 B); the reduction buffer red
// (8*8*33*4 = 8448 B) reuses the same storage after a barrier.
constexpr int LDS_BYTES = 32768;

// ---------------------------------------------------------------------------
// Fused kernel, r11: 512 blocks x 512 threads (2 blocks/CU) so one block's
// circuit tail + barrier stalls overlap the other block's phase-1 stream.
// Per-thread work and coalescing identical to r7 (8-lane clusters read
// 128 B contiguous; 32 rows/thread).
// Experiment ledger (do not retry):
//   r4  nt on 50% of stream      -> +26 us   (nt gets worse service)
//   r5  Ro/Ri phase-split        -> +13 us   (interleaved dual-stream wins)
//   r7  X global->LDS            -> -1.2 us  (kept)
//   r8  nt on 6% slice           -> neutral, FETCH unchanged (IC memory-side,
//                                   allocation not steerable from flags)
//   r9  tail spread 16w x 16lane -> +13 us   (wave64 VALU cost is per-wave;
//                                   never mask lanes to spread serial work)
// Structural wall: Ro+Ri = exactly 256 MiB = Infinity Cache capacity ->
// ~50% hit rate under cyclic replay; ~5.2 TB/s mixed service, FETCH pinned
// at ~131 MB across all variants.
// ---------------------------------------------------------------------------

template<int LVL>
__device__ __forceinline__ void build64(float* st, float c, float s) {
    #pragma unroll
    for (int i = (1 << LVL) - 1; i >= 0; --i) {  // downward: in-place safe
        const float v = st[i];
        st[2 * i]     = v * c;
        st[2 * i + 1] = v * s;
    }
}

template<int W>   // W in [2..7], lane-local RY
__device__ __forceinline__ void ry64(float* st, float c, float s) {
    constexpr int STRIDE = 1 << (7 - W);
    #pragma unroll
    for (int base = 0; base < 64; base += 2 * STRIDE)
        #pragma unroll
        for (int j = 0; j < STRIDE; ++j) {
            const int i0 = base + j, i1 = i0 + STRIDE;
            const float a0 = st[i0], a1 = st[i1];
            st[i0] = fmaf(c, a0, -(s * a1));
            st[i1] = fmaf(s, a0,   c * a1);
        }
}

// RY on qubit 0 or 1 (lane bits). mask: 2 for q0, 1 for q1. mybit: lane's bit.
__device__ __forceinline__ void ry_cross(float* st, float c, float s, int mask, int mybit) {
    const float ss = mybit ? s : -s;
    #pragma unroll
    for (int j = 0; j < 64; ++j) {
        const float other = __shfl_xor(st[j], mask, 64);
        st[j] = fmaf(c, st[j], ss * other);
    }
}

template<int CB, int TB>   // both bits inside the 64-reg index: free permutation
__device__ __forceinline__ void cx_reg(float* st) {
    #pragma unroll
    for (int i = 0; i < 64; ++i)
        if ((i & CB) && !(i & TB)) {
            const float t = st[i]; st[i] = st[i | TB]; st[i | TB] = t;
        }
}

__global__ __launch_bounds__(BLK, 4) void fused_edgenet(
    const float* __restrict__ X,
    const float* __restrict__ Ri,
    const float* __restrict__ Ro,
    const float* __restrict__ theta,
    float* __restrict__ out)
{
    __shared__ __align__(16) char ldsbuf[LDS_BYTES];
    float4* xs  = reinterpret_cast<float4*>(ldsbuf);       // [2048] in phase 1
    float*  red = reinterpret_cast<float*>(ldsbuf);        // [8][8][33] after

    const int tid  = threadIdx.x;
    const int w    = tid >> 6;
    const int lane = tid & 63;
    const int gl   = lane & (NGRP - 1);      // group-lane [0,8)
    const int ks   = lane >> 3;              // in-wave k-sub-slice [0,8)
    const int g    = blockIdx.x * NGRP + gl; // global float4-group

    const float4* Ro4 = reinterpret_cast<const float4*>(Ro);
    const float4* Ri4 = reinterpret_cast<const float4*>(Ri);
    const float4* X4  = reinterpret_cast<const float4*>(X);

    // stage the FULL X into LDS: 2048 float4, 4 per thread, coalesced
    #pragma unroll
    for (int i = 0; i < 4; ++i) xs[tid + i * BLK] = X4[tid + i * BLK];
    __syncthreads();

    // ---------------- Phase 1: GEMM partials (all waves) ----------------
    float acc_o[4][4];
    float acc_i[4][4];
    #pragma unroll
    for (int el = 0; el < 4; ++el)
        #pragma unroll
        for (int q = 0; q < 4; ++q) { acc_o[el][q] = 0.f; acc_i[el][q] = 0.f; }

    const int n0 = w * ROWS_W + ks * ROWS_T;
    #pragma unroll 4
    for (int k = 0; k < ROWS_T; ++k) {
        const int n = n0 + k;
        const float4 ro = Ro4[(size_t)n * (N_EDGES / 4) + g];
        const float4 ri = Ri4[(size_t)n * (N_EDGES / 4) + g];
        const float4 x  = xs[n];             // ds_read_b128, 8-lane broadcast
        const float roa[4] = {ro.x, ro.y, ro.z, ro.w};
        const float ria[4] = {ri.x, ri.y, ri.z, ri.w};
        const float xa[4]  = {x.x,  x.y,  x.z,  x.w};
        #pragma unroll
        for (int el = 0; el < 4; ++el)
            #pragma unroll
            for (int q = 0; q < 4; ++q) {
                acc_o[el][q] = fmaf(roa[el], xa[q], acc_o[el][q]);
                acc_i[el][q] = fmaf(ria[el], xa[q], acc_i[el][q]);
            }
    }

    // in-wave reduce over ks (lane bits 3,4,5): wave-level 256-row partials
    float sum[32];
    #pragma unroll
    for (int q = 0; q < 4; ++q)
        #pragma unroll
        for (int el = 0; el < 4; ++el) {
            sum[q * 4 + el]      = acc_o[el][q];
            sum[16 + q * 4 + el] = acc_i[el][q];
        }
    #pragma unroll
    for (int v = 0; v < 32; ++v) {
        sum[v] += __shfl_xor(sum[v], 8, 64);
        sum[v] += __shfl_xor(sum[v], 16, 64);
        sum[v] += __shfl_xor(sum[v], 32, 64);
    }

    __syncthreads();                         // all xs reads done -> reuse LDS
    if (ks == 0) {                           // stride-33 words -> conflict-free
        #pragma unroll
        for (int v = 0; v < 32; ++v) red[(w * NGRP + gl) * 33 + v] = sum[v];
    }
    __syncthreads();

    // ---------------- Phase 2: circuit (threads 0..127 only) ----------------
    if (tid < 4 * TILE_E) {
        const int sub   = tid & 3;                 // quad sub-lane: i[7:6]
        const int e_loc = tid >> 2;                // [0,32) edge within tile
        const int g2    = e_loc >> 2;              // group of this edge
        const int el    = e_loc & 3;               // element within group
        const int e     = blockIdx.x * TILE_E + e_loc;
        const int p0    = (sub >> 1) & 1;          // qubit-0 bit
        const int p1    = sub & 1;                 // qubit-1 bit

        // gather: each quad-lane sums 2 of the 8 wave-partials, quad-reduce
        float a[8] = {0.f, 0.f, 0.f, 0.f, 0.f, 0.f, 0.f, 0.f};
        #pragma unroll
        for (int r = 0; r < 2; ++r) {
            const int ww = sub * 2 + r;
            #pragma unroll
            for (int q = 0; q < 4; ++q) {
                a[q]     += red[(ww * NGRP + g2) * 33 + q * 4 + el];
                a[4 + q] += red[(ww * NGRP + g2) * 33 + 16 + q * 4 + el];
            }
        }
        #pragma unroll
        for (int q = 0; q < 8; ++q) {
            a[q] += __shfl_xor(a[q], 1, 64);
            a[q] += __shfl_xor(a[q], 2, 64);
        }

        // initial product state (full range reduction: angles are large)
        float st[64];
        {
            float c, s, f;
            sincosf(0.5f * a[0], &s, &c); f  = p0 ? s : c;
            sincosf(0.5f * a[1], &s, &c); f *= p1 ? s : c;
            st[0] = f;
            sincosf(0.5f * a[2], &s, &c); build64<0>(st, c, s);
            sincosf(0.5f * a[3], &s, &c); build64<1>(st, c, s);
            sincosf(0.5f * a[4], &s, &c); build64<2>(st, c, s);
            sincosf(0.5f * a[5], &s, &c); build64<3>(st, c, s);
            sincosf(0.5f * a[6], &s, &c); build64<4>(st, c, s);
            sincosf(0.5f * a[7], &s, &c); build64<5>(st, c, s);
        }

        // circuit (theta/2 bounded -> fast sincos)
#define THC(IDX) float c_, s_; __sincosf(0.5f * theta[IDX], &s_, &c_)
#define RYL(W, IDX) { THC(IDX); ry64<W>(st, c_, s_); }
#define RY0(IDX)    { THC(IDX); ry_cross(st, c_, s_, 2, p0); }
#define RY1(IDX)    { THC(IDX); ry_cross(st, c_, s_, 1, p1); }

        RY1(0) RYL(2, 1)
        {   // cx(1,2): control = lane bit p1, target = reg bit5
            #pragma unroll
            for (int j = 0; j < 32; ++j) {
                const float t0 = st[j], t1 = st[j + 32];
                st[j]      = p1 ? t1 : t0;
                st[j + 32] = p1 ? t0 : t1;
            }
        }
        RYL(5, 2) RYL(6, 3) cx_reg<2, 4>(st);           // cx(6,5)
        RY0(4) RY1(5)
        {   // cx(0,1): control = p0, target = lane bit p1 -> sub 2<->3 swap
            #pragma unroll
            for (int j = 0; j < 64; ++j) {
                const float other = __shfl_xor(st[j], 1, 64);
                st[j] = p0 ? other : st[j];
            }
        }
        RYL(2, 6) RYL(3, 7) cx_reg<16, 32>(st);         // cx(3,2)
        RYL(4, 8) RYL(5, 9) cx_reg<8, 4>(st);           // cx(4,5)
        RYL(6, 10) RYL(7, 11) cx_reg<1, 2>(st);         // cx(7,6)
        RYL(2, 12) RYL(5, 13) cx_reg<32, 4>(st);        // cx(2,5)
        RY1(14) RYL(2, 15)
        {   // cx(1,2) again
            #pragma unroll
            for (int j = 0; j < 32; ++j) {
                const float t0 = st[j], t1 = st[j + 32];
                st[j]      = p1 ? t1 : t0;
                st[j + 32] = p1 ? t0 : t1;
            }
        }
        RYL(5, 16) RYL(6, 17) cx_reg<2, 4>(st);         // cx(6,5)
        RYL(2, 18) RYL(5, 19) cx_reg<32, 4>(st);        // cx(2,5)
        RYL(5, 20)
#undef RYL
#undef RY0
#undef RY1
#undef THC

        // measure qubit 5 (reg bit 2): d = m1 - m0, reduce over quad
        float m0 = 0.f, m1 = 0.f;
        #pragma unroll
        for (int j = 0; j < 64; ++j) {
            if (j & 4) m1 = fmaf(st[j], st[j], m1);
            else       m0 = fmaf(st[j], st[j], m0);
        }
        float d = m1 - m0;
        d += __shfl_xor(d, 1, 64);
        d += __shfl_xor(d, 2, 64);
        if (sub == 0) out[e] = 0.5f * (1.0f + d);
    }
}

// ---------------------------------------------------------------------------
extern "C" void kernel_launch(void* const* d_in, const int* in_sizes, int n_in,
                              void* d_out, int out_size, void* d_ws, size_t ws_size,
                              hipStream_t stream)
{
    const float* X     = (const float*)d_in[0];
    const float* Ri    = (const float*)d_in[1];
    const float* Ro    = (const float*)d_in[2];
    const float* theta = (const float*)d_in[3];
    float* outp = (float*)d_out;

    fused_edgenet<<<dim3(NBLK), dim3(BLK), 0, stream>>>(X, Ri, Ro, theta, outp);
}

// Round 12
// 56.308 us; speedup vs baseline: 1.1356x; 1.1356x over previous
//
#include <hip/hip_runtime.h>
#include <cstdint>

constexpr int N_NODES = 2048;
constexpr int N_EDGES = 16384;
constexpr int NGRP    = 16;                 // float4 groups per block -> 64 edges
constexpr int TILE_E  = NGRP * 4;           // 64 edges per block
constexpr int WAVES   = 16;
constexpr int BLK     = WAVES * 64;         // 1024 threads
constexpr int ROWS_W  = N_NODES / WAVES;    // 128 rows per wave
constexpr int ROWS_T  = ROWS_W / 4;         // 32 rows per thread
constexpr int NBLK    = N_EDGES / TILE_E;   // 256 blocks -> 1 block/CU

// LDS union: phase 1 uses xs (X staged, 32768 B); the reduction buffer red
// (16*16*33*4 = 33792 B) reuses the same storage after a barrier.
constexpr int LDS_BYTES = 33792;

// ---------------------------------------------------------------------------
// Fused kernel (r7/r10 structure = best known, 56.4 us, reproduced twice):
//   GEMM-partial phase (16 waves, full K) -> LDS reduce ->
//   circuit phase on threads 0..255 (4 waves, ALL 64 lanes active).
// Experiment ledger (do not retry):
//   r4  nt on 50% of stream      -> +26 us   (nt gets worse service)
//   r5  Ro/Ri phase-split        -> +13 us   (interleaved dual-stream wins)
//   r7  X global->LDS            -> -1.2 us  (kept)
//   r8  nt on 6% slice           -> neutral, FETCH unchanged (IC memory-side,
//                                   allocation not steerable from flags)
//   r9  tail spread 16w x 16lane -> +13 us   (wave64 VALU cost is per-wave;
//                                   never mask lanes to spread serial work)
//   r11 2 blocks/CU (512x512)    -> +7.5 us  (halved per-row segment 256->128B;
//                                   don't trade stream granularity for
//                                   occupancy tricks)
// Structural wall: Ro+Ri = exactly 256 MiB = Infinity Cache capacity ->
// ~50% hit rate under cyclic replay (replacement not steerable). Phase 1
// runs at ~5.2 TB/s mixed L3/HBM service = 84% of the 6.29 TB/s measured
// copy ceiling. FETCH_SIZE pinned at ~131 MB across ALL variants.
// ---------------------------------------------------------------------------

template<int LVL>
__device__ __forceinline__ void build64(float* st, float c, float s) {
    #pragma unroll
    for (int i = (1 << LVL) - 1; i >= 0; --i) {  // downward: in-place safe
        const float v = st[i];
        st[2 * i]     = v * c;
        st[2 * i + 1] = v * s;
    }
}

template<int W>   // W in [2..7], lane-local RY
__device__ __forceinline__ void ry64(float* st, float c, float s) {
    constexpr int STRIDE = 1 << (7 - W);
    #pragma unroll
    for (int base = 0; base < 64; base += 2 * STRIDE)
        #pragma unroll
        for (int j = 0; j < STRIDE; ++j) {
            const int i0 = base + j, i1 = i0 + STRIDE;
            const float a0 = st[i0], a1 = st[i1];
            st[i0] = fmaf(c, a0, -(s * a1));
            st[i1] = fmaf(s, a0,   c * a1);
        }
}

// RY on qubit 0 or 1 (lane bits). mask: 2 for q0, 1 for q1. mybit: lane's bit.
__device__ __forceinline__ void ry_cross(float* st, float c, float s, int mask, int mybit) {
    const float ss = mybit ? s : -s;
    #pragma unroll
    for (int j = 0; j < 64; ++j) {
        const float other = __shfl_xor(st[j], mask, 64);
        st[j] = fmaf(c, st[j], ss * other);
    }
}

template<int CB, int TB>   // both bits inside the 64-reg index: free permutation
__device__ __forceinline__ void cx_reg(float* st) {
    #pragma unroll
    for (int i = 0; i < 64; ++i)
        if ((i & CB) && !(i & TB)) {
            const float t = st[i]; st[i] = st[i | TB]; st[i | TB] = t;
        }
}

__global__ __launch_bounds__(BLK, 4) void fused_edgenet(
    const float* __restrict__ X,
    const float* __restrict__ Ri,
    const float* __restrict__ Ro,
    const float* __restrict__ theta,
    float* __restrict__ out)
{
    __shared__ __align__(16) char ldsbuf[LDS_BYTES];
    float4* xs  = reinterpret_cast<float4*>(ldsbuf);       // [2048] in phase 1
    float*  red = reinterpret_cast<float*>(ldsbuf);        // [16][16][33] after

    const int tid  = threadIdx.x;
    const int w    = tid >> 6;
    const int lane = tid & 63;
    const int gl   = lane & 15;              // group-lane
    const int ks   = lane >> 4;              // in-wave k-sub-slice [0,4)
    const int g    = blockIdx.x * NGRP + gl; // global float4-group

    const float4* Ro4 = reinterpret_cast<const float4*>(Ro);
    const float4* Ri4 = reinterpret_cast<const float4*>(Ri);
    const float4* X4  = reinterpret_cast<const float4*>(X);

    // stage the FULL X into LDS: 2048 float4, 2 per thread, coalesced
    xs[tid]        = X4[tid];
    xs[tid + 1024] = X4[tid + 1024];
    __syncthreads();

    // ---------------- Phase 1: GEMM partials (all waves) ----------------
    float acc_o[4][4];
    float acc_i[4][4];
    #pragma unroll
    for (int el = 0; el < 4; ++el)
        #pragma unroll
        for (int q = 0; q < 4; ++q) { acc_o[el][q] = 0.f; acc_i[el][q] = 0.f; }

    const int n0 = w * ROWS_W + ks * ROWS_T;
    #pragma unroll 4
    for (int k = 0; k < ROWS_T; ++k) {
        const int n = n0 + k;
        const float4 ro = Ro4[(size_t)n * (N_EDGES / 4) + g];
        const float4 ri = Ri4[(size_t)n * (N_EDGES / 4) + g];
        const float4 x  = xs[n];             // ds_read_b128, broadcast
        const float roa[4] = {ro.x, ro.y, ro.z, ro.w};
        const float ria[4] = {ri.x, ri.y, ri.z, ri.w};
        const float xa[4]  = {x.x,  x.y,  x.z,  x.w};
        #pragma unroll
        for (int el = 0; el < 4; ++el)
            #pragma unroll
            for (int q = 0; q < 4; ++q) {
                acc_o[el][q] = fmaf(roa[el], xa[q], acc_o[el][q]);
                acc_i[el][q] = fmaf(ria[el], xa[q], acc_i[el][q]);
            }
    }

    // in-wave reduce over ks (lane bits 4,5): wave-level 128-row partials
    float sum[32];
    #pragma unroll
    for (int q = 0; q < 4; ++q)
        #pragma unroll
        for (int el = 0; el < 4; ++el) {
            sum[q * 4 + el]      = acc_o[el][q];
            sum[16 + q * 4 + el] = acc_i[el][q];
        }
    #pragma unroll
    for (int v = 0; v < 32; ++v) {
        sum[v] += __shfl_xor(sum[v], 16, 64);
        sum[v] += __shfl_xor(sum[v], 32, 64);
    }

    __syncthreads();                         // all xs reads done -> reuse LDS
    if (ks == 0) {                           // stride-33 words -> conflict-free
        #pragma unroll
        for (int v = 0; v < 32; ++v) red[(w * NGRP + gl) * 33 + v] = sum[v];
    }
    __syncthreads();

    // ---------------- Phase 2: circuit (threads 0..255 only) ----------------
    if (tid < 4 * TILE_E) {
        const int sub   = tid & 3;                 // quad sub-lane: i[7:6]
        const int e_loc = tid >> 2;                // [0,64) edge within tile
        const int g2    = e_loc >> 2;              // group of this edge
        const int el    = e_loc & 3;               // element within group
        const int e     = blockIdx.x * TILE_E + e_loc;
        const int p0    = (sub >> 1) & 1;          // qubit-0 bit
        const int p1    = sub & 1;                 // qubit-1 bit

        // gather: each quad-lane sums 4 of the 16 wave-partials, quad-reduce
        float a[8] = {0.f, 0.f, 0.f, 0.f, 0.f, 0.f, 0.f, 0.f};
        #pragma unroll
        for (int r = 0; r < 4; ++r) {
            const int ww = sub * 4 + r;
            #pragma unroll
            for (int q = 0; q < 4; ++q) {
                a[q]     += red[(ww * NGRP + g2) * 33 + q * 4 + el];
                a[4 + q] += red[(ww * NGRP + g2) * 33 + 16 + q * 4 + el];
            }
        }
        #pragma unroll
        for (int q = 0; q < 8; ++q) {
            a[q] += __shfl_xor(a[q], 1, 64);
            a[q] += __shfl_xor(a[q], 2, 64);
        }

        // initial product state (full range reduction: angles are large)
        float st[64];
        {
            float c, s, f;
            sincosf(0.5f * a[0], &s, &c); f  = p0 ? s : c;
            sincosf(0.5f * a[1], &s, &c); f *= p1 ? s : c;
            st[0] = f;
            sincosf(0.5f * a[2], &s, &c); build64<0>(st, c, s);
            sincosf(0.5f * a[3], &s, &c); build64<1>(st, c, s);
            sincosf(0.5f * a[4], &s, &c); build64<2>(st, c, s);
            sincosf(0.5f * a[5], &s, &c); build64<3>(st, c, s);
            sincosf(0.5f * a[6], &s, &c); build64<4>(st, c, s);
            sincosf(0.5f * a[7], &s, &c); build64<5>(st, c, s);
        }

        // circuit (theta/2 bounded -> fast sincos)
#define THC(IDX) float c_, s_; __sincosf(0.5f * theta[IDX], &s_, &c_)
#define RYL(W, IDX) { THC(IDX); ry64<W>(st, c_, s_); }
#define RY0(IDX)    { THC(IDX); ry_cross(st, c_, s_, 2, p0); }
#define RY1(IDX)    { THC(IDX); ry_cross(st, c_, s_, 1, p1); }

        RY1(0) RYL(2, 1)
        {   // cx(1,2): control = lane bit p1, target = reg bit5
            #pragma unroll
            for (int j = 0; j < 32; ++j) {
                const float t0 = st[j], t1 = st[j + 32];
                st[j]      = p1 ? t1 : t0;
                st[j + 32] = p1 ? t0 : t1;
            }
        }
        RYL(5, 2) RYL(6, 3) cx_reg<2, 4>(st);           // cx(6,5)
        RY0(4) RY1(5)
        {   // cx(0,1): control = p0, target = lane bit p1 -> sub 2<->3 swap
            #pragma unroll
            for (int j = 0; j < 64; ++j) {
                const float other = __shfl_xor(st[j], 1, 64);
                st[j] = p0 ? other : st[j];
            }
        }
        RYL(2, 6) RYL(3, 7) cx_reg<16, 32>(st);         // cx(3,2)
        RYL(4, 8) RYL(5, 9) cx_reg<8, 4>(st);           // cx(4,5)
        RYL(6, 10) RYL(7, 11) cx_reg<1, 2>(st);         // cx(7,6)
        RYL(2, 12) RYL(5, 13) cx_reg<32, 4>(st);        // cx(2,5)
        RY1(14) RYL(2, 15)
        {   // cx(1,2) again
            #pragma unroll
            for (int j = 0; j < 32; ++j) {
                const float t0 = st[j], t1 = st[j + 32];
                st[j]      = p1 ? t1 : t0;
                st[j + 32] = p1 ? t0 : t1;
            }
        }
        RYL(5, 16) RYL(6, 17) cx_reg<2, 4>(st);         // cx(6,5)
        RYL(2, 18) RYL(5, 19) cx_reg<32, 4>(st);        // cx(2,5)
        RYL(5, 20)
#undef RYL
#undef RY0
#undef RY1
#undef THC

        // measure qubit 5 (reg bit 2): d = m1 - m0, reduce over quad
        float m0 = 0.f, m1 = 0.f;
        #pragma unroll
        for (int j = 0; j < 64; ++j) {
            if (j & 4) m1 = fmaf(st[j], st[j], m1);
            else       m0 = fmaf(st[j], st[j], m0);
        }
        float d = m1 - m0;
        d += __shfl_xor(d, 1, 64);
        d += __shfl_xor(d, 2, 64);
        if (sub == 0) out[e] = 0.5f * (1.0f + d);
    }
}

// ---------------------------------------------------------------------------
extern "C" void kernel_launch(void* const* d_in, const int* in_sizes, int n_in,
                              void* d_out, int out_size, void* d_ws, size_t ws_size,
                              hipStream_t stream)
{
    const float* X     = (const float*)d_in[0];
    const float* Ri    = (const float*)d_in[1];
    const float* Ro    = (const float*)d_in[2];
    const float* theta = (const float*)d_in[3];
    float* outp = (float*)d_out;

    fused_edgenet<<<dim3(NBLK), dim3(BLK), 0, stream>>>(X, Ri, Ro, theta, outp);
}